// Round 6
// baseline (1060.872 us; speedup 1.0000x reference)
//
#include <hip/hip_runtime.h>
#include <math.h>

#define WIDTH 512
#define LAYERS 6
#define HEADS 8
#define DH 64
#define T_DYN 16
#define NF 128
#define NFR 12            // N = N_FRAMES-1
#define BLK 146           // NF + T_DYN + 2
#define SEQ 1752          // NFR * BLK
#define BATCH 4
#define VOCAB 1024
#define MROWS (BATCH*SEQ)      // 7008
#define MPAD 7040              // 55*128, OOB-row padding for tail tile
#define OUTROWS (BATCH*NFR*NF) // 6144

typedef __bf16 bf16_t;
typedef __bf16 bf16x8 __attribute__((ext_vector_type(8)));
typedef __bf16 bf16x4 __attribute__((ext_vector_type(4)));
typedef float f32x4 __attribute__((ext_vector_type(4)));

// counted vmcnt wait: does NOT drain the load queue (T4, m218)
#define WAITVM(N) asm volatile("s_waitcnt vmcnt(" #N ")" ::: "memory")

// async global -> LDS, 16B per lane; LDS dest is wave-uniform base + lane*16
__device__ __forceinline__ void gload16(const bf16_t* g, bf16_t* l) {
    __builtin_amdgcn_global_load_lds(
        (const __attribute__((address_space(1))) void*)g,
        (__attribute__((address_space(3))) void*)l, 16, 0, 0);
}

// fast exact-gelu: erf via Abramowitz-Stegun 7.1.26 (|err| <= 1.5e-7,
// far below bf16 quantization). ~12 VALU ops vs ~40 for libm erff.
__device__ __forceinline__ float gelu_f(float v) {
    float ax = fabsf(v) * 0.70710678118654752f;
    float t = __builtin_amdgcn_rcpf(1.f + 0.3275911f * ax);
    float p = ((((1.061405429f * t - 1.453152027f) * t + 1.421413741f) * t
                - 0.284496736f) * t + 0.254829592f) * t;
    float erfv = 1.f - p * __expf(-ax * ax);
    erfv = (v < 0.f) ? -erfv : erfv;
    return 0.5f * v * (1.f + erfv);
}

// ---------------- fp32 -> bf16 cast of ALL weights in one launch ----------------
// outputs are contiguous in the workspace in segment order; inputs are 5 pointers
__global__ __launch_bounds__(256) void cast_all_kernel(
    const float* __restrict__ s0, const float* __restrict__ s1,
    const float* __restrict__ s2, const float* __restrict__ s3,
    const float* __restrict__ s4, bf16_t* __restrict__ out,
    int n0, int n1, int n2, int n3, int ntot) {
    int i = blockIdx.x * 256 + threadIdx.x;
    if (i >= ntot) return;
    int off = i;
    const float* src;
    if (off < n0) { src = s0; }
    else { off -= n0;
        if (off < n1) { src = s1; }
        else { off -= n1;
            if (off < n2) { src = s2; }
            else { off -= n2;
                if (off < n3) { src = s3; }
                else { off -= n3; src = s4; }
            }
        }
    }
    float4 v = ((const float4*)src)[off];
    bf16x4 o = { (bf16_t)v.x, (bf16_t)v.y, (bf16_t)v.z, (bf16_t)v.w };
    *(bf16x4*)(out + (size_t)i * 4) = o;
}

// ---------------- embed: h = concat(x, delim, f, delim) + pos (fp32) ----------------
__global__ __launch_bounds__(256) void embed_kernel(
    const float* __restrict__ x, const float* __restrict__ f,
    const float* __restrict__ delim, float* __restrict__ h) {
    int idx = blockIdx.x * 256 + threadIdx.x;
    if (idx >= BATCH * SEQ * WIDTH) return;
    int w = idx & (WIDTH - 1);
    int bs = idx >> 9;
    int s = bs % SEQ;
    int b = bs / SEQ;
    int bi = s / BLK, r = s % BLK;
    float v;
    if (r < NF) {
        v = x[(((size_t)b * NFR + bi) * NF + r) * WIDTH + w];
    } else if (r == NF || r == BLK - 1) {
        v = delim[w];
    } else {
        v = f[(((size_t)b * NFR + bi) * T_DYN + (r - NF - 1)) * WIDTH + w];
    }
    int j = w >> 1;
    float denom = powf(10000.f, (float)j * (1.f / 256.f));
    float ang = (float)s / denom;
    v += (w & 1) ? cosf(ang) : sinf(ang);
    h[idx] = v;
}

// ---------------- fused LN -> bf16 (one wave per row): a_bf = LN(h)*g + b ----------------
__global__ __launch_bounds__(256) void ln_bf16_kernel(
    const float* __restrict__ h, const float* __restrict__ g,
    const float* __restrict__ bb, bf16_t* __restrict__ out) {
    int row = blockIdx.x * 4 + (threadIdx.x >> 6);
    int lane = threadIdx.x & 63;
    const float* p = h + (size_t)row * WIDTH + lane * 8;
    float4 a = *(const float4*)p;
    float4 c = *(const float4*)(p + 4);
    float s = a.x + a.y + a.z + a.w + c.x + c.y + c.z + c.w;
    float q = a.x*a.x + a.y*a.y + a.z*a.z + a.w*a.w
            + c.x*c.x + c.y*c.y + c.z*c.z + c.w*c.w;
    #pragma unroll
    for (int o = 32; o > 0; o >>= 1) {
        s += __shfl_xor(s, o);
        q += __shfl_xor(q, o);
    }
    float mean = s * (1.f / WIDTH);
    float rstd = rsqrtf(q * (1.f / WIDTH) - mean * mean + 1e-5f);
    const float* gp = g + lane * 8;
    const float* bp = bb + lane * 8;
    float4 g0 = *(const float4*)gp, g1 = *(const float4*)(gp + 4);
    float4 b0 = *(const float4*)bp, b1 = *(const float4*)(bp + 4);
    bf16x8 o8;
    o8[0] = (bf16_t)((a.x - mean) * rstd * g0.x + b0.x);
    o8[1] = (bf16_t)((a.y - mean) * rstd * g0.y + b0.y);
    o8[2] = (bf16_t)((a.z - mean) * rstd * g0.z + b0.z);
    o8[3] = (bf16_t)((a.w - mean) * rstd * g0.w + b0.w);
    o8[4] = (bf16_t)((c.x - mean) * rstd * g1.x + b1.x);
    o8[5] = (bf16_t)((c.y - mean) * rstd * g1.y + b1.y);
    o8[6] = (bf16_t)((c.z - mean) * rstd * g1.z + b1.z);
    o8[7] = (bf16_t)((c.w - mean) * rstd * g1.w + b1.w);
    *(bf16x8*)(out + (size_t)row * WIDTH + lane * 8) = o8;
}

// ---------------- gather+cast h rows for the prediction head ----------------
__global__ __launch_bounds__(256) void gather_bf16_kernel(
    const float* __restrict__ h, bf16_t* __restrict__ out) {
    int idx = blockIdx.x * 256 + threadIdx.x;   // one 8-elem chunk each
    int row = idx >> 6;
    int ch = (idx & 63) * 8;
    int b = row / (NFR * NF);
    int rem = row - b * (NFR * NF);
    int n = rem >> 7, ii = rem & 127;
    const float* p = h + ((size_t)(b * SEQ + n * BLK + ii)) * WIDTH + ch;
    float4 a = *(const float4*)p, c = *(const float4*)(p + 4);
    bf16x8 o8 = { (bf16_t)a.x, (bf16_t)a.y, (bf16_t)a.z, (bf16_t)a.w,
                  (bf16_t)c.x, (bf16_t)c.y, (bf16_t)c.z, (bf16_t)c.w };
    *(bf16x8*)(out + (size_t)row * WIDTH + ch) = o8;
}

// ---------------- bf16 MFMA GEMM, 4-deep counted-vmcnt pipeline ----------------
// C[M,N] = A[M,K] @ W[N,K]^T + bias.  A, W pre-cast bf16.  TNV = N tile (128 or 64).
// C_MODE 0: fp32 store   C_MODE 1: gelu -> bf16 (restage, TNV=128)
// C_MODE 2: fp32 +=      C_MODE 3: bf16 (restage, TNV=128)
// Pipeline (T3+T4, depth 4): 4 LDS buffers; per K-step {vmcnt(2*LOADS) ->
// raw s_barrier -> stage tile t+3 -> compute tile t}. Three tiles stay in
// flight across barriers; tile t's loads get 3 compute-phases of latency cover.
// Tail ladder: vmcnt(2L) -> vmcnt(L) -> vmcnt(0) as staging stops.
// T1: bijective XCD-aware block remap (m204) so blocks sharing an A row-panel
// run on the SAME XCD (private L2).
// LDS layout per buffer: A rows [0,TM) then W rows [0,TNV), row-major [row][TK],
// 8-elem chunks XOR-swizzled by (row>>1)&3 applied on the global SOURCE address
// (global_load_lds dest must stay linear, m104/m173); reads use matching swizzle.
#define TM 128
#define TK 32
#define CPAD 68   // restage row stride (bf16)

template<int C_MODE, int TNV>
__global__ __launch_bounds__(256) void gemm_f(
    const bf16_t* __restrict__ A,
    const bf16_t* __restrict__ Wb, const float* __restrict__ bias,
    float* __restrict__ Cf, bf16_t* __restrict__ Cb,
    int M, int N, int K) {
    constexpr int RI = (TNV == 128) ? 4 : 2;
    constexpr int BUFE = (TM + TNV) * TK;          // bf16 elements per buffer
    constexpr int STAGE4 = 4 * BUFE * 2;           // bytes (quad buffer)
    constexpr int REST = 4 * 64 * CPAD * 2;
    constexpr int SMEM_SIZE = (C_MODE == 1 || C_MODE == 3)
                              ? (STAGE4 > REST ? STAGE4 : REST) : STAGE4;
    __shared__ __align__(16) char smem[SMEM_SIZE];
    bf16_t* b0 = (bf16_t*)smem;
    bf16_t* b1 = b0 + BUFE;
    bf16_t* b2 = b1 + BUFE;
    bf16_t* b3 = b2 + BUFE;

    int tid = threadIdx.x;
    // T1 XCD-aware bijective remap (speed heuristic only; correct for any grid)
    int gx = gridDim.x;
    int nwg = gx * gridDim.y;
    int wg = blockIdx.y * gx + blockIdx.x;          // hw linear id, x fastest
    int q8 = nwg >> 3, r8 = nwg & 7;
    int xcd = wg & 7, idx8 = wg >> 3;
    int lid = xcd * q8 + (xcd < r8 ? xcd : r8) + idx8;
    int by = lid / gx;
    int bx = lid - by * gx;
    int bm = by * TM, bn = bx * TNV;

    int lane = tid & 63, wid = tid >> 6;
    int wy, wx, wrb;
    if (TNV == 128) { wy = wid >> 1; wx = wid & 1; wrb = wy * 64; }
    else            { wy = wid;      wx = 0;       wrb = wy * 32; }
    int lr = lane & 15, lq = lane >> 4;
    f32x4 acc[RI][4];
    #pragma unroll
    for (int i = 0; i < RI; i++)
        #pragma unroll
        for (int j = 0; j < 4; j++)
            acc[i][j] = (f32x4){0.f, 0.f, 0.f, 0.f};

    // staging geometry: per issue, a wave's 64 lanes fill 16 LDS rows (1 KB)
    int r0 = wid * 16 + (lane >> 2);       // rows 0..63 across 4 waves
    int r1 = r0 + 64;                      // rows 64..127
    int c0 = ((lane & 3) - (r0 >> 1)) & 3; // pre-swizzled source chunk
    int c1 = ((lane & 3) - (r1 >> 1)) & 3;
    const bf16_t* gA0 = A + (size_t)(bm + r0) * K + c0 * 8;
    const bf16_t* gA1 = A + (size_t)(bm + r1) * K + c1 * 8;
    const bf16_t* gW0 = Wb + (size_t)(bn + r0) * K + c0 * 8;
    const bf16_t* gW1 = (TNV == 128) ? (Wb + (size_t)(bn + r1) * K + c1 * 8) : nullptr;
    // wave-uniform LDS element offsets within a buffer
    int lA0o = wid * 512;
    int lA1o = (4 + wid) * 512;
    int lW0o = TM * TK + wid * 512;
    int lW1o = TM * TK + (4 + wid) * 512;

    // precomputed read offsets (swizzled)
    int offA[RI], offB[4];
    #pragma unroll
    for (int i = 0; i < RI; i++) {
        int rowa = wrb + i * 16 + lr;
        offA[i] = rowa * TK + (((lq + (rowa >> 1)) & 3) * 8);
    }
    #pragma unroll
    for (int j = 0; j < 4; j++) {
        int rowb = wx * 64 + j * 16 + lr;
        offB[j] = TM * TK + rowb * TK + (((lq + (rowb >> 1)) & 3) * 8);
    }

    auto stage = [&](bf16_t* buf) {
        gload16(gA0, buf + lA0o); gA0 += TK;
        gload16(gA1, buf + lA1o); gA1 += TK;
        gload16(gW0, buf + lW0o); gW0 += TK;
        if constexpr (TNV == 128) { gload16(gW1, buf + lW1o); gW1 += TK; }
    };
    auto compute = [&](const bf16_t* buf) {
        bf16x8 af[RI], bfr[4];
        #pragma unroll
        for (int i = 0; i < RI; i++) af[i] = *(const bf16x8*)(buf + offA[i]);
        #pragma unroll
        for (int j = 0; j < 4; j++) bfr[j] = *(const bf16x8*)(buf + offB[j]);
        #pragma unroll
        for (int i = 0; i < RI; i++)
            #pragma unroll
            for (int j = 0; j < 4; j++)
                acc[i][j] = __builtin_amdgcn_mfma_f32_16x16x32_bf16(af[i], bfr[j], acc[i][j], 0, 0, 0);
    };

    int nt = K / TK;               // >= 16
    bf16_t* p0 = b0;               // compute buffer (tile t)
    bf16_t* p1 = b1;               // tile t+1 (in flight)
    bf16_t* p2 = b2;               // tile t+2 (in flight)
    bf16_t* p3 = b3;               // stage target (tile t+3)
    stage(p0);
    stage(p1);
    stage(p2);
    for (int t = 0; t < nt; ++t) {
        // wait for tile t only; tiles t+1/t+2 stay in flight across the barrier
        if (t < nt - 2) {
            if constexpr (TNV == 128) WAITVM(8); else WAITVM(6);
        } else if (t < nt - 1) {
            if constexpr (TNV == 128) WAITVM(4); else WAITVM(3);
        } else {
            WAITVM(0);
        }
        __builtin_amdgcn_s_barrier();
        if (t + 3 < nt) stage(p3);
        compute(p0);
        bf16_t* tmp = p0; p0 = p1; p1 = p2; p2 = p3; p3 = tmp;
    }

    if constexpr (C_MODE == 1 || C_MODE == 3) {
        __syncthreads();   // full drain before restage reuses the stage LDS
        // restage through per-wave LDS, then full-line bf16x8 stores (TNV==128)
        bf16_t* Cw = (bf16_t*)smem + wid * 64 * CPAD;
        #pragma unroll
        for (int j = 0; j < 4; j++) {
            int col = bn + wx * 64 + j * 16 + lr;
            float bj = bias ? bias[col] : 0.f;
            #pragma unroll
            for (int i = 0; i < RI; i++) {
                #pragma unroll
                for (int r = 0; r < 4; r++) {
                    float v = acc[i][j][r] + bj;
                    if (C_MODE == 1) v = gelu_f(v);
                    Cw[(i * 16 + lq * 4 + r) * CPAD + j * 16 + lr] = (bf16_t)v;
                }
            }
        }
        // wave-private region: no barrier needed
        #pragma unroll
        for (int it2 = 0; it2 < 8; it2++) {
            int row_l = (lane >> 3) + it2 * 8;
            int seg = lane & 7;
            int gm = bm + wy * 64 + row_l;
            if (gm < M)
                *(bf16x8*)(Cb + (size_t)gm * N + bn + wx * 64 + seg * 8) =
                    *(const bf16x8*)(Cw + row_l * CPAD + seg * 8);
        }
    } else {
        #pragma unroll
        for (int j = 0; j < 4; j++) {
            int col = bn + wx * 64 + j * 16 + lr;
            float bj = bias ? bias[col] : 0.f;
            #pragma unroll
            for (int i = 0; i < RI; i++) {
                int rbase = bm + wrb + i * 16 + lq * 4;
                #pragma unroll
                for (int r = 0; r < 4; r++) {
                    int gm = rbase + r;
                    if (gm >= M) continue;
                    float v = acc[i][j][r] + bj;
                    if (C_MODE == 2) Cf[(size_t)gm * N + col] += v;
                    else             Cf[(size_t)gm * N + col] = v;
                }
            }
        }
    }
}

// ---------------- structured-mask attention (MFMA) ----------------
__device__ __forceinline__ int key_of(int t, int bi) {
    if (bi > 0) { if (t == 0) return bi * BLK - 1; t -= 1; }
    if (t < NF) return bi * BLK + t;
    t -= NF;
    int j = t / 17, r = t % 17;
    return j * BLK + NF + r;
}

#define KC 64           // keys per chunk
#define KR 72           // padded LDS row length

// block = (bi, h, b), 256 threads = 4 waves; wave w owns q rows [w*32, w*32+32)
// also copies this (bi,h,b)'s 18 self-only rows (o = v) at entry
__global__ __launch_bounds__(256) void attn_mfma(
    const bf16_t* __restrict__ qkv, bf16_t* __restrict__ o) {
    int bi = blockIdx.x;
    int h = blockIdx.y, b = blockIdx.z;
    int tid = threadIdx.x;
    int lane = tid & 63, wid = tid >> 6;
    int col = lane & 15, lq = lane >> 4;
    int qr0 = wid * 32;
    const bf16_t* base = qkv + (size_t)b * SEQ * (3 * WIDTH);

    __shared__ bf16_t Ks[KC * KR];        // [key][dim], pad 72
    __shared__ bf16_t Vt[DH * KR];        // [dim][key], pad 72
    __shared__ bf16_t Ps[4][32 * KR];     // per-wave P / O staging
    __shared__ int slist[352];

    // self-only rows for this (bi,h,b): 18 rows x 64 dims = 144 bf16x8 copies
    if (tid < 144) {
        int row = NF + (tid >> 3), g = tid & 7;
        int s = bi * BLK + row;
        *(bf16x8*)(o + ((size_t)(b * SEQ) + s) * WIDTH + h * DH + g * 8) =
            *(const bf16x8*)(base + (size_t)s * (3 * WIDTH) + 2 * WIDTH + h * DH + g * 8);
    }

    int na = (bi > 0 ? 1 : 0) + NF + 17 * (bi + 1);   // <= 333
    for (int t = tid; t < na; t += 256) slist[t] = key_of(t, bi);

    bf16x8 af_q[2][2];
    #pragma unroll
    for (int i = 0; i < 2; i++) {
        int s = bi * BLK + qr0 + i * 16 + col;
        const bf16_t* qp = base + (size_t)s * (3 * WIDTH) + h * DH;
        #pragma unroll
        for (int m = 0; m < 2; m++)
            af_q[i][m] = *(const bf16x8*)(qp + m * 32 + lq * 8);
    }

    f32x4 Oacc[2][4];
    #pragma unroll
    for (int i = 0; i < 2; i++)
        #pragma unroll
        for (int od = 0; od < 4; od++)
            Oacc[i][od] = (f32x4){0.f, 0.f, 0.f, 0.f};
    float m_r[2][4], l_r[2][4];
    #pragma unroll
    for (int i = 0; i < 2; i++)
        #pragma unroll
        for (int r = 0; r < 4; r++) { m_r[i][r] = -INFINITY; l_r[i][r] = 0.f; }

    __syncthreads();   // slist ready

    int nch = (na + KC - 1) / KC;
    const bf16_t z0 = (bf16_t)0.f;
    for (int ci = 0; ci < nch; ci++) {
        int kbase = ci * KC;
        #pragma unroll
        for (int it = 0; it < 2; it++) {
            int idx = tid + it * 256;      // 0..511
            int key = idx >> 3, g = idx & 7;
            int tkey = kbase + key;
            bf16x8 kv = {z0,z0,z0,z0,z0,z0,z0,z0};
            bf16x8 vv = kv;
            if (tkey < na) {
                int sk = slist[tkey];
                const bf16_t* kp = base + (size_t)sk * (3 * WIDTH) + WIDTH + h * DH + g * 8;
                kv = *(const bf16x8*)kp;
                vv = *(const bf16x8*)(kp + WIDTH);
            }
            *(bf16x8*)(Ks + key * KR + g * 8) = kv;
            #pragma unroll
            for (int j = 0; j < 8; j++) Vt[(g * 8 + j) * KR + key] = vv[j];
        }
        __syncthreads();

        f32x4 Sacc[2][4];
        #pragma unroll
        for (int i = 0; i < 2; i++)
            #pragma unroll
            for (int kj = 0; kj < 4; kj++)
                Sacc[i][kj] = (f32x4){0.f, 0.f, 0.f, 0.f};
        #pragma unroll
        for (int m = 0; m < 2; m++) {
            #pragma unroll
            for (int kj = 0; kj < 4; kj++) {
                bf16x8 bf_k = *(const bf16x8*)(Ks + (kj * 16 + col) * KR + m * 32 + lq * 8);
                #pragma unroll
                for (int i = 0; i < 2; i++)
                    Sacc[i][kj] = __builtin_amdgcn_mfma_f32_16x16x32_bf16(af_q[i][m], bf_k, Sacc[i][kj], 0, 0, 0);
            }
        }

        float alpha_[2][4];
        #pragma unroll
        for (int i = 0; i < 2; i++) {
            #pragma unroll
            for (int r = 0; r < 4; r++) {
                #pragma unroll
                for (int kj = 0; kj < 4; kj++) {
                    int kidx = kbase + kj * 16 + col;
                    float s = Sacc[i][kj][r] * 0.125f;
                    Sacc[i][kj][r] = (kidx < na) ? s : -INFINITY;
                }
                float mx = fmaxf(fmaxf(Sacc[i][0][r], Sacc[i][1][r]),
                                 fmaxf(Sacc[i][2][r], Sacc[i][3][r]));
                mx = fmaxf(mx, __shfl_xor(mx, 1));
                mx = fmaxf(mx, __shfl_xor(mx, 2));
                mx = fmaxf(mx, __shfl_xor(mx, 4));
                mx = fmaxf(mx, __shfl_xor(mx, 8));
                float mn = fmaxf(m_r[i][r], mx);
                float al = __expf(m_r[i][r] - mn);
                float ps = 0.f;
                #pragma unroll
                for (int kj = 0; kj < 4; kj++) {
                    float p = __expf(Sacc[i][kj][r] - mn);
                    Sacc[i][kj][r] = p;
                    ps += p;
                }
                ps += __shfl_xor(ps, 1);
                ps += __shfl_xor(ps, 2);
                ps += __shfl_xor(ps, 4);
                ps += __shfl_xor(ps, 8);
                l_r[i][r] = l_r[i][r] * al + ps;
                m_r[i][r] = mn;
                alpha_[i][r] = al;
            }
        }
        #pragma unroll
        for (int i = 0; i < 2; i++)
            #pragma unroll
            for (int od = 0; od < 4; od++)
                #pragma unroll
                for (int r = 0; r < 4; r++)
                    Oacc[i][od][r] *= alpha_[i][r];

        bf16_t* Pw = Ps[wid];
        #pragma unroll
        for (int i = 0; i < 2; i++)
            #pragma unroll
            for (int kj = 0; kj < 4; kj++)
                #pragma unroll
                for (int r = 0; r < 4; r++)
                    Pw[(i * 16 + lq * 4 + r) * KR + kj * 16 + col] = (bf16_t)Sacc[i][kj][r];
        __syncthreads();

        #pragma unroll
        for (int m = 0; m < 2; m++) {
            bf16x8 afp[2];
            #pragma unroll
            for (int i = 0; i < 2; i++)
                afp[i] = *(const bf16x8*)(Pw + (i * 16 + col) * KR + m * 32 + lq * 8);
            #pragma unroll
            for (int od = 0; od < 4; od++) {
                bf16x8 vf = *(const bf16x8*)(Vt + (od * 16 + col) * KR + m * 32 + lq * 8);
                #pragma unroll
                for (int i = 0; i < 2; i++)
                    Oacc[i][od] = __builtin_amdgcn_mfma_f32_16x16x32_bf16(afp[i], vf, Oacc[i][od], 0, 0, 0);
            }
        }
        __syncthreads();
    }

    bf16_t* Pw = Ps[wid];
    float inv[2][4];
    #pragma unroll
    for (int i = 0; i < 2; i++)
        #pragma unroll
        for (int r = 0; r < 4; r++) inv[i][r] = 1.f / l_r[i][r];
    #pragma unroll
    for (int i = 0; i < 2; i++)
        #pragma unroll
        for (int od = 0; od < 4; od++)
            #pragma unroll
            for (int r = 0; r < 4; r++)
                Pw[(i * 16 + lq * 4 + r) * KR + od * 16 + col] = (bf16_t)(Oacc[i][od][r] * inv[i][r]);
    __syncthreads();
    #pragma unroll
    for (int it = 0; it < 4; it++) {
        int idx = lane + it * 64;
        int row = idx >> 3, g = idx & 7;
        int gs = bi * BLK + qr0 + row;
        *(bf16x8*)(o + ((size_t)(b * SEQ + gs)) * WIDTH + h * DH + g * 8) =
            *(const bf16x8*)(Pw + row * KR + g * 8);
    }
}

extern "C" void kernel_launch(void* const* d_in, const int* in_sizes, int n_in,
                              void* d_out, int out_size, void* d_ws, size_t ws_size,
                              hipStream_t stream) {
    const float* x     = (const float*)d_in[0];
    const float* f     = (const float*)d_in[1];
    const float* delim = (const float*)d_in[2];
    const float* ln1_s = (const float*)d_in[3];
    const float* ln1_b = (const float*)d_in[4];
    const float* w_qkv = (const float*)d_in[5];
    const float* b_qkv = (const float*)d_in[6];
    const float* w_out = (const float*)d_in[7];
    const float* b_out = (const float*)d_in[8];
    const float* ln2_s = (const float*)d_in[9];
    const float* ln2_b = (const float*)d_in[10];
    const float* w_fc  = (const float*)d_in[11];
    const float* b_fc  = (const float*)d_in[12];
    const float* w_pr  = (const float*)d_in[13];
    const float* b_pr  = (const float*)d_in[14];
    const float* w_hd  = (const float*)d_in[15];
    float* out = (float*)d_out;

    // workspace layout (~89 MB):
    // h fp32 (14.35) | big_bf MPAD x 2048 (28.8; qkv uses 1536-wide, o_bf aliases tail)
    // | a_bf MPAD x 512 (7.2; gather head buffer aliases it) | bf16 weights (38.8,
    //   contiguous in cast_all segment order: wi, wo, wfc, wpr, wh)
    char* base = (char*)d_ws;
    float*  h      = (float*)base;    base += (size_t)MROWS * WIDTH * 4;
    bf16_t* big_bf = (bf16_t*)base;   base += (size_t)MPAD * 2048 * 2;
    bf16_t* o_bf   = big_bf + (size_t)MPAD * 1536;   // tail alias: MPAD*512 bf16
    bf16_t* a_bf   = (bf16_t*)base;   base += (size_t)MPAD * 512 * 2;
    bf16_t* g_bf   = a_bf;            // head gather buffer (post-layers lifetime)
    bf16_t* wi_bf  = (bf16_t*)base;   base += (size_t)LAYERS * 1536 * 512 * 2;
    bf16_t* wo_bf  = (bf16_t*)base;   base += (size_t)LAYERS * 512 * 512 * 2;
    bf16_t* wfc_bf = (bf16_t*)base;   base += (size_t)LAYERS * 2048 * 512 * 2;
    bf16_t* wpr_bf = (bf16_t*)base;   base += (size_t)LAYERS * 512 * 2048 * 2;
    bf16_t* wh_bf  = (bf16_t*)base;   base += (size_t)VOCAB * 512 * 2;

    // hoisted weight casts: ONE kernel over all 5 segments (outputs contiguous)
    {
        const int n0 = LAYERS * 1536 * 512 / 4;
        const int n1 = LAYERS * 512 * 512 / 4;
        const int n2 = LAYERS * 2048 * 512 / 4;
        const int n3 = LAYERS * 512 * 2048 / 4;
        const int n4c = VOCAB * 512 / 4;
        const int ntot = n0 + n1 + n2 + n3 + n4c;
        cast_all_kernel<<<(ntot + 255) / 256, 256, 0, stream>>>(
            w_qkv, w_out, w_fc, w_pr, w_hd, wi_bf, n0, n1, n2, n3, ntot);
    }

    embed_kernel<<<(BATCH * SEQ * WIDTH) / 256, 256, 0, stream>>>(x, f, delim, h);

    const int MT = (MROWS + TM - 1) / TM;   // 55
    for (int l = 0; l < LAYERS; l++) {
        ln_bf16_kernel<<<MROWS / 4, 256, 0, stream>>>(h, ln1_s + l * WIDTH, ln1_b + l * WIDTH, a_bf);
        gemm_f<3, 128><<<dim3(1536 / 128, MT), 256, 0, stream>>>(
            a_bf, wi_bf + (size_t)l * 1536 * 512, b_qkv + (size_t)l * 1536,
            nullptr, big_bf, MROWS, 1536, 512);
        attn_mfma<<<dim3(NFR, HEADS, BATCH), 256, 0, stream>>>(big_bf, o_bf);
        gemm_f<2, 64><<<dim3(512 / 64, MT), 256, 0, stream>>>(
            o_bf, wo_bf + (size_t)l * 512 * 512, b_out + (size_t)l * 512,
            h, nullptr, MROWS, 512, 512);
        ln_bf16_kernel<<<MROWS / 4, 256, 0, stream>>>(h, ln2_s + l * WIDTH, ln2_b + l * WIDTH, a_bf);
        gemm_f<1, 128><<<dim3(2048 / 128, MT), 256, 0, stream>>>(
            a_bf, wfc_bf + (size_t)l * 2048 * 512, b_fc + (size_t)l * 2048,
            nullptr, big_bf, MROWS, 2048, 512);
        gemm_f<2, 64><<<dim3(512 / 64, MT), 256, 0, stream>>>(
            big_bf, wpr_bf + (size_t)l * 512 * 2048, b_pr + (size_t)l * 512,
            h, nullptr, MROWS, 512, 2048);
    }

    gather_bf16_kernel<<<OUTROWS * 64 / 256, 256, 0, stream>>>(h, g_bf);
    gemm_f<0, 64><<<dim3(VOCAB / 64, OUTROWS / TM), 256, 0, stream>>>(
        g_bf, wh_bf, nullptr, out, nullptr, OUTROWS, VOCAB, 512);
}

// Round 7
// 979.764 us; speedup vs baseline: 1.0828x; 1.0828x over previous
//
#include <hip/hip_runtime.h>
#include <math.h>

#define WIDTH 512
#define LAYERS 6
#define HEADS 8
#define DH 64
#define T_DYN 16
#define NF 128
#define NFR 12            // N = N_FRAMES-1
#define BLK 146           // NF + T_DYN + 2
#define SEQ 1752          // NFR * BLK
#define BATCH 4
#define VOCAB 1024
#define MROWS (BATCH*SEQ)      // 7008
#define MPAD 7040              // 55*128, OOB-row padding for tail tile
#define OUTROWS (BATCH*NFR*NF) // 6144

typedef __bf16 bf16_t;
typedef __bf16 bf16x8 __attribute__((ext_vector_type(8)));
typedef __bf16 bf16x4 __attribute__((ext_vector_type(4)));
typedef float f32x4 __attribute__((ext_vector_type(4)));

// counted vmcnt wait: does NOT drain the load queue (T4, m218)
#define WAITVM(N) asm volatile("s_waitcnt vmcnt(" #N ")" ::: "memory")

// async global -> LDS, 16B per lane; LDS dest is wave-uniform base + lane*16
__device__ __forceinline__ void gload16(const bf16_t* g, bf16_t* l) {
    __builtin_amdgcn_global_load_lds(
        (const __attribute__((address_space(1))) void*)g,
        (__attribute__((address_space(3))) void*)l, 16, 0, 0);
}

// fast exact-gelu: erf via Abramowitz-Stegun 7.1.26 (|err| <= 1.5e-7,
// far below bf16 quantization). ~12 VALU ops vs ~40 for libm erff.
__device__ __forceinline__ float gelu_f(float v) {
    float ax = fabsf(v) * 0.70710678118654752f;
    float t = __builtin_amdgcn_rcpf(1.f + 0.3275911f * ax);
    float p = ((((1.061405429f * t - 1.453152027f) * t + 1.421413741f) * t
                - 0.284496736f) * t + 0.254829592f) * t;
    float erfv = 1.f - p * __expf(-ax * ax);
    erfv = (v < 0.f) ? -erfv : erfv;
    return 0.5f * v * (1.f + erfv);
}

// ---------------- fp32 -> bf16 cast of ALL weights in one launch ----------------
// outputs are contiguous in the workspace in segment order; inputs are 5 pointers
__global__ __launch_bounds__(256) void cast_all_kernel(
    const float* __restrict__ s0, const float* __restrict__ s1,
    const float* __restrict__ s2, const float* __restrict__ s3,
    const float* __restrict__ s4, bf16_t* __restrict__ out,
    int n0, int n1, int n2, int n3, int ntot) {
    int i = blockIdx.x * 256 + threadIdx.x;
    if (i >= ntot) return;
    int off = i;
    const float* src;
    if (off < n0) { src = s0; }
    else { off -= n0;
        if (off < n1) { src = s1; }
        else { off -= n1;
            if (off < n2) { src = s2; }
            else { off -= n2;
                if (off < n3) { src = s3; }
                else { off -= n3; src = s4; }
            }
        }
    }
    float4 v = ((const float4*)src)[off];
    bf16x4 o = { (bf16_t)v.x, (bf16_t)v.y, (bf16_t)v.z, (bf16_t)v.w };
    *(bf16x4*)(out + (size_t)i * 4) = o;
}

// ---------------- embed: h = concat(x, delim, f, delim) + pos (fp32) ----------------
__global__ __launch_bounds__(256) void embed_kernel(
    const float* __restrict__ x, const float* __restrict__ f,
    const float* __restrict__ delim, float* __restrict__ h) {
    int idx = blockIdx.x * 256 + threadIdx.x;
    if (idx >= BATCH * SEQ * WIDTH) return;
    int w = idx & (WIDTH - 1);
    int bs = idx >> 9;
    int s = bs % SEQ;
    int b = bs / SEQ;
    int bi = s / BLK, r = s % BLK;
    float v;
    if (r < NF) {
        v = x[(((size_t)b * NFR + bi) * NF + r) * WIDTH + w];
    } else if (r == NF || r == BLK - 1) {
        v = delim[w];
    } else {
        v = f[(((size_t)b * NFR + bi) * T_DYN + (r - NF - 1)) * WIDTH + w];
    }
    int j = w >> 1;
    float denom = powf(10000.f, (float)j * (1.f / 256.f));
    float ang = (float)s / denom;
    v += (w & 1) ? cosf(ang) : sinf(ang);
    h[idx] = v;
}

// ---------------- fused LN -> bf16 (one wave per row): a_bf = LN(h)*g + b ----------------
__global__ __launch_bounds__(256) void ln_bf16_kernel(
    const float* __restrict__ h, const float* __restrict__ g,
    const float* __restrict__ bb, bf16_t* __restrict__ out) {
    int row = blockIdx.x * 4 + (threadIdx.x >> 6);
    int lane = threadIdx.x & 63;
    const float* p = h + (size_t)row * WIDTH + lane * 8;
    float4 a = *(const float4*)p;
    float4 c = *(const float4*)(p + 4);
    float s = a.x + a.y + a.z + a.w + c.x + c.y + c.z + c.w;
    float q = a.x*a.x + a.y*a.y + a.z*a.z + a.w*a.w
            + c.x*c.x + c.y*c.y + c.z*c.z + c.w*c.w;
    #pragma unroll
    for (int o = 32; o > 0; o >>= 1) {
        s += __shfl_xor(s, o);
        q += __shfl_xor(q, o);
    }
    float mean = s * (1.f / WIDTH);
    float rstd = rsqrtf(q * (1.f / WIDTH) - mean * mean + 1e-5f);
    const float* gp = g + lane * 8;
    const float* bp = bb + lane * 8;
    float4 g0 = *(const float4*)gp, g1 = *(const float4*)(gp + 4);
    float4 b0 = *(const float4*)bp, b1 = *(const float4*)(bp + 4);
    bf16x8 o8;
    o8[0] = (bf16_t)((a.x - mean) * rstd * g0.x + b0.x);
    o8[1] = (bf16_t)((a.y - mean) * rstd * g0.y + b0.y);
    o8[2] = (bf16_t)((a.z - mean) * rstd * g0.z + b0.z);
    o8[3] = (bf16_t)((a.w - mean) * rstd * g0.w + b0.w);
    o8[4] = (bf16_t)((c.x - mean) * rstd * g1.x + b1.x);
    o8[5] = (bf16_t)((c.y - mean) * rstd * g1.y + b1.y);
    o8[6] = (bf16_t)((c.z - mean) * rstd * g1.z + b1.z);
    o8[7] = (bf16_t)((c.w - mean) * rstd * g1.w + b1.w);
    *(bf16x8*)(out + (size_t)row * WIDTH + lane * 8) = o8;
}

// ---------------- gather+cast h rows for the prediction head ----------------
__global__ __launch_bounds__(256) void gather_bf16_kernel(
    const float* __restrict__ h, bf16_t* __restrict__ out) {
    int idx = blockIdx.x * 256 + threadIdx.x;   // one 8-elem chunk each
    int row = idx >> 6;
    int ch = (idx & 63) * 8;
    int b = row / (NFR * NF);
    int rem = row - b * (NFR * NF);
    int n = rem >> 7, ii = rem & 127;
    const float* p = h + ((size_t)(b * SEQ + n * BLK + ii)) * WIDTH + ch;
    float4 a = *(const float4*)p, c = *(const float4*)(p + 4);
    bf16x8 o8 = { (bf16_t)a.x, (bf16_t)a.y, (bf16_t)a.z, (bf16_t)a.w,
                  (bf16_t)c.x, (bf16_t)c.y, (bf16_t)c.z, (bf16_t)c.w };
    *(bf16x8*)(out + (size_t)row * WIDTH + ch) = o8;
}

// ---------------- bf16 MFMA GEMM, 3-deep counted-vmcnt pipeline ----------------
// C[M,N] = A[M,K] @ W[N,K]^T + bias.  A, W pre-cast bf16.  TNV = N tile (128 or 64).
// C_MODE 0: fp32 store (restage, TNV=64)   C_MODE 1: gelu -> bf16 (restage, TNV=128)
// C_MODE 2: fp32 += (restage, TNV=64)      C_MODE 3: bf16 (restage, TNV=128)
// Pipeline (T3+T4): 3 LDS buffers; per K-step {vmcnt(LOADS) -> raw s_barrier ->
// stage tile t+2 -> compute tile t}. vmcnt never drained to 0 in the loop.
// T1: bijective XCD-aware block remap (m204).
// All epilogues restage acc through per-wave LDS so global stores are
// full-line coalesced (bf16x8 or dwordx4); the fp32 restage uses row stride
// 68 f32 (272 B) -> 2-way banks in both phases (free, m136).
#define TM 128
#define TK 32
#define CPAD 68   // bf16 restage row stride
#define RPAD 68   // fp32 restage row stride (keeps 16B alignment: 68*4=272)

template<int C_MODE, int TNV>
__global__ __launch_bounds__(256) void gemm_f(
    const bf16_t* __restrict__ A,
    const bf16_t* __restrict__ Wb, const float* __restrict__ bias,
    float* __restrict__ Cf, bf16_t* __restrict__ Cb,
    int M, int N, int K) {
    constexpr int RI = (TNV == 128) ? 4 : 2;
    constexpr int BUFE = (TM + TNV) * TK;          // bf16 elements per buffer
    constexpr int STAGE3 = 3 * BUFE * 2;           // bytes (triple buffer)
    constexpr int RESTB = 4 * 64 * CPAD * 2;       // bf16 restage bytes
    constexpr int REST3 = 4 * 32 * RPAD * 4;       // fp32 restage bytes (TNV=64)
    constexpr int RESTX = (C_MODE == 1 || C_MODE == 3) ? RESTB : REST3;
    constexpr int SMEM_SIZE = (STAGE3 > RESTX ? STAGE3 : RESTX);
    __shared__ __align__(16) char smem[SMEM_SIZE];
    bf16_t* b0 = (bf16_t*)smem;
    bf16_t* b1 = b0 + BUFE;
    bf16_t* b2 = b1 + BUFE;

    int tid = threadIdx.x;
    // T1 XCD-aware bijective remap (speed heuristic only; correct for any grid)
    int gx = gridDim.x;
    int nwg = gx * gridDim.y;
    int wg = blockIdx.y * gx + blockIdx.x;          // hw linear id, x fastest
    int q8 = nwg >> 3, r8 = nwg & 7;
    int xcd = wg & 7, idx8 = wg >> 3;
    int lid = xcd * q8 + (xcd < r8 ? xcd : r8) + idx8;
    int by = lid / gx;
    int bx = lid - by * gx;
    int bm = by * TM, bn = bx * TNV;

    int lane = tid & 63, wid = tid >> 6;
    int wy, wx, wrb;
    if (TNV == 128) { wy = wid >> 1; wx = wid & 1; wrb = wy * 64; }
    else            { wy = wid;      wx = 0;       wrb = wy * 32; }
    int lr = lane & 15, lq = lane >> 4;
    f32x4 acc[RI][4];
    #pragma unroll
    for (int i = 0; i < RI; i++)
        #pragma unroll
        for (int j = 0; j < 4; j++)
            acc[i][j] = (f32x4){0.f, 0.f, 0.f, 0.f};

    // staging geometry: per issue, a wave's 64 lanes fill 16 LDS rows (1 KB)
    int r0 = wid * 16 + (lane >> 2);       // rows 0..63 across 4 waves
    int r1 = r0 + 64;                      // rows 64..127
    int c0 = ((lane & 3) - (r0 >> 1)) & 3; // pre-swizzled source chunk
    int c1 = ((lane & 3) - (r1 >> 1)) & 3;
    const bf16_t* gA0 = A + (size_t)(bm + r0) * K + c0 * 8;
    const bf16_t* gA1 = A + (size_t)(bm + r1) * K + c1 * 8;
    const bf16_t* gW0 = Wb + (size_t)(bn + r0) * K + c0 * 8;
    const bf16_t* gW1 = (TNV == 128) ? (Wb + (size_t)(bn + r1) * K + c1 * 8) : nullptr;
    // wave-uniform LDS element offsets within a buffer
    int lA0o = wid * 512;
    int lA1o = (4 + wid) * 512;
    int lW0o = TM * TK + wid * 512;
    int lW1o = TM * TK + (4 + wid) * 512;

    // precomputed read offsets (swizzled)
    int offA[RI], offB[4];
    #pragma unroll
    for (int i = 0; i < RI; i++) {
        int rowa = wrb + i * 16 + lr;
        offA[i] = rowa * TK + (((lq + (rowa >> 1)) & 3) * 8);
    }
    #pragma unroll
    for (int j = 0; j < 4; j++) {
        int rowb = wx * 64 + j * 16 + lr;
        offB[j] = TM * TK + rowb * TK + (((lq + (rowb >> 1)) & 3) * 8);
    }

    auto stage = [&](bf16_t* buf) {
        gload16(gA0, buf + lA0o); gA0 += TK;
        gload16(gA1, buf + lA1o); gA1 += TK;
        gload16(gW0, buf + lW0o); gW0 += TK;
        if constexpr (TNV == 128) { gload16(gW1, buf + lW1o); gW1 += TK; }
    };
    auto compute = [&](const bf16_t* buf) {
        bf16x8 af[RI], bfr[4];
        #pragma unroll
        for (int i = 0; i < RI; i++) af[i] = *(const bf16x8*)(buf + offA[i]);
        #pragma unroll
        for (int j = 0; j < 4; j++) bfr[j] = *(const bf16x8*)(buf + offB[j]);
        #pragma unroll
        for (int i = 0; i < RI; i++)
            #pragma unroll
            for (int j = 0; j < 4; j++)
                acc[i][j] = __builtin_amdgcn_mfma_f32_16x16x32_bf16(af[i], bfr[j], acc[i][j], 0, 0, 0);
    };

    int nt = K / TK;               // >= 16
    bf16_t* bufc = b0;             // compute buffer (tile t)
    bf16_t* bufn = b1;             // tile t+1 (in flight)
    bf16_t* bufs = b2;             // stage target (tile t+2)
    stage(bufc);
    stage(bufn);
    for (int t = 0; t < nt; ++t) {
        if (t < nt - 1) {
            // tile t's loads done; tile t+1's (LOADS) may stay in flight
            if constexpr (TNV == 128) WAITVM(4); else WAITVM(3);
        } else {
            WAITVM(0);
        }
        __builtin_amdgcn_s_barrier();
        if (t + 2 < nt) stage(bufs);
        compute(bufc);
        bf16_t* tmp = bufc; bufc = bufn; bufn = bufs; bufs = tmp;
    }

    if constexpr (C_MODE == 1 || C_MODE == 3) {
        __syncthreads();   // all waves done with K-loop LDS before restage reuse
        // restage through per-wave LDS, then full-line bf16x8 stores (TNV==128)
        bf16_t* Cw = (bf16_t*)smem + wid * 64 * CPAD;
        #pragma unroll
        for (int j = 0; j < 4; j++) {
            int col = bn + wx * 64 + j * 16 + lr;
            float bj = bias ? bias[col] : 0.f;
            #pragma unroll
            for (int i = 0; i < RI; i++) {
                #pragma unroll
                for (int r = 0; r < 4; r++) {
                    float v = acc[i][j][r] + bj;
                    if (C_MODE == 1) v = gelu_f(v);
                    Cw[(i * 16 + lq * 4 + r) * CPAD + j * 16 + lr] = (bf16_t)v;
                }
            }
        }
        // wave-private region: no barrier needed
        #pragma unroll
        for (int it2 = 0; it2 < 8; it2++) {
            int row_l = (lane >> 3) + it2 * 8;
            int seg = lane & 7;
            int gm = bm + wy * 64 + row_l;
            if (gm < M)
                *(bf16x8*)(Cb + (size_t)gm * N + bn + wx * 64 + seg * 8) =
                    *(const bf16x8*)(Cw + row_l * CPAD + seg * 8);
        }
    } else if constexpr (TNV == 64) {
        // fp32 restage: per-wave 32x64 f32 region (stride RPAD), then coalesced
        // dwordx4 store / read-modify-write. Identical arithmetic to the old
        // scalar path (acc + bias [+ Cf]).
        __syncthreads();   // all waves done with K-loop LDS before restage reuse
        float* Cw = (float*)smem + wid * 32 * RPAD;
        #pragma unroll
        for (int j = 0; j < 4; j++) {
            int col = bn + j * 16 + lr;
            float bj = bias ? bias[col] : 0.f;
            #pragma unroll
            for (int i = 0; i < RI; i++)
                #pragma unroll
                for (int r = 0; r < 4; r++)
                    Cw[(i * 16 + lq * 4 + r) * RPAD + j * 16 + lr] = acc[i][j][r] + bj;
        }
        // wave-private region: no barrier needed
        #pragma unroll
        for (int it2 = 0; it2 < 8; it2++) {
            int row_l = it2 * 4 + (lane >> 4);
            int seg = lane & 15;
            int gm = bm + wrb + row_l;
            if (gm < M) {
                float* gp = Cf + (size_t)gm * N + bn + seg * 4;
                f32x4 v = *(const f32x4*)(Cw + row_l * RPAD + seg * 4);
                if (C_MODE == 2) {
                    f32x4 o = *(const f32x4*)gp;
                    v = v + o;
                }
                *(f32x4*)gp = v;
            }
        }
    } else {
        // generic scalar fallback (unused by the launcher)
        #pragma unroll
        for (int j = 0; j < 4; j++) {
            int col = bn + wx * 64 + j * 16 + lr;
            float bj = bias ? bias[col] : 0.f;
            #pragma unroll
            for (int i = 0; i < RI; i++) {
                int rbase = bm + wrb + i * 16 + lq * 4;
                #pragma unroll
                for (int r = 0; r < 4; r++) {
                    int gm = rbase + r;
                    if (gm >= M) continue;
                    float v = acc[i][j][r] + bj;
                    if (C_MODE == 2) Cf[(size_t)gm * N + col] += v;
                    else             Cf[(size_t)gm * N + col] = v;
                }
            }
        }
    }
}

// ---------------- structured-mask attention (MFMA) ----------------
__device__ __forceinline__ int key_of(int t, int bi) {
    if (bi > 0) { if (t == 0) return bi * BLK - 1; t -= 1; }
    if (t < NF) return bi * BLK + t;
    t -= NF;
    int j = t / 17, r = t % 17;
    return j * BLK + NF + r;
}

#define KC 64           // keys per chunk
#define KR 72           // padded LDS row length

// block = (bi, h, b), 256 threads = 4 waves; wave w owns q rows [w*32, w*32+32)
// also copies this (bi,h,b)'s 18 self-only rows (o = v) at entry
__global__ __launch_bounds__(256) void attn_mfma(
    const bf16_t* __restrict__ qkv, bf16_t* __restrict__ o) {
    int bi = blockIdx.x;
    int h = blockIdx.y, b = blockIdx.z;
    int tid = threadIdx.x;
    int lane = tid & 63, wid = tid >> 6;
    int col = lane & 15, lq = lane >> 4;
    int qr0 = wid * 32;
    const bf16_t* base = qkv + (size_t)b * SEQ * (3 * WIDTH);

    __shared__ bf16_t Ks[KC * KR];        // [key][dim], pad 72
    __shared__ bf16_t Vt[DH * KR];        // [dim][key], pad 72
    __shared__ bf16_t Ps[4][32 * KR];     // per-wave P / O staging
    __shared__ int slist[352];

    // self-only rows for this (bi,h,b): 18 rows x 64 dims = 144 bf16x8 copies
    if (tid < 144) {
        int row = NF + (tid >> 3), g = tid & 7;
        int s = bi * BLK + row;
        *(bf16x8*)(o + ((size_t)(b * SEQ) + s) * WIDTH + h * DH + g * 8) =
            *(const bf16x8*)(base + (size_t)s * (3 * WIDTH) + 2 * WIDTH + h * DH + g * 8);
    }

    int na = (bi > 0 ? 1 : 0) + NF + 17 * (bi + 1);   // <= 333
    for (int t = tid; t < na; t += 256) slist[t] = key_of(t, bi);

    bf16x8 af_q[2][2];
    #pragma unroll
    for (int i = 0; i < 2; i++) {
        int s = bi * BLK + qr0 + i * 16 + col;
        const bf16_t* qp = base + (size_t)s * (3 * WIDTH) + h * DH;
        #pragma unroll
        for (int m = 0; m < 2; m++)
            af_q[i][m] = *(const bf16x8*)(qp + m * 32 + lq * 8);
    }

    f32x4 Oacc[2][4];
    #pragma unroll
    for (int i = 0; i < 2; i++)
        #pragma unroll
        for (int od = 0; od < 4; od++)
            Oacc[i][od] = (f32x4){0.f, 0.f, 0.f, 0.f};
    float m_r[2][4], l_r[2][4];
    #pragma unroll
    for (int i = 0; i < 2; i++)
        #pragma unroll
        for (int r = 0; r < 4; r++) { m_r[i][r] = -INFINITY; l_r[i][r] = 0.f; }

    __syncthreads();   // slist ready

    int nch = (na + KC - 1) / KC;
    const bf16_t z0 = (bf16_t)0.f;
    for (int ci = 0; ci < nch; ci++) {
        int kbase = ci * KC;
        #pragma unroll
        for (int it = 0; it < 2; it++) {
            int idx = tid + it * 256;      // 0..511
            int key = idx >> 3, g = idx & 7;
            int tkey = kbase + key;
            bf16x8 kv = {z0,z0,z0,z0,z0,z0,z0,z0};
            bf16x8 vv = kv;
            if (tkey < na) {
                int sk = slist[tkey];
                const bf16_t* kp = base + (size_t)sk * (3 * WIDTH) + WIDTH + h * DH + g * 8;
                kv = *(const bf16x8*)kp;
                vv = *(const bf16x8*)(kp + WIDTH);
            }
            *(bf16x8*)(Ks + key * KR + g * 8) = kv;
            #pragma unroll
            for (int j = 0; j < 8; j++) Vt[(g * 8 + j) * KR + key] = vv[j];
        }
        __syncthreads();

        f32x4 Sacc[2][4];
        #pragma unroll
        for (int i = 0; i < 2; i++)
            #pragma unroll
            for (int kj = 0; kj < 4; kj++)
                Sacc[i][kj] = (f32x4){0.f, 0.f, 0.f, 0.f};
        #pragma unroll
        for (int m = 0; m < 2; m++) {
            #pragma unroll
            for (int kj = 0; kj < 4; kj++) {
                bf16x8 bf_k = *(const bf16x8*)(Ks + (kj * 16 + col) * KR + m * 32 + lq * 8);
                #pragma unroll
                for (int i = 0; i < 2; i++)
                    Sacc[i][kj] = __builtin_amdgcn_mfma_f32_16x16x32_bf16(af_q[i][m], bf_k, Sacc[i][kj], 0, 0, 0);
            }
        }

        float alpha_[2][4];
        #pragma unroll
        for (int i = 0; i < 2; i++) {
            #pragma unroll
            for (int r = 0; r < 4; r++) {
                #pragma unroll
                for (int kj = 0; kj < 4; kj++) {
                    int kidx = kbase + kj * 16 + col;
                    float s = Sacc[i][kj][r] * 0.125f;
                    Sacc[i][kj][r] = (kidx < na) ? s : -INFINITY;
                }
                float mx = fmaxf(fmaxf(Sacc[i][0][r], Sacc[i][1][r]),
                                 fmaxf(Sacc[i][2][r], Sacc[i][3][r]));
                mx = fmaxf(mx, __shfl_xor(mx, 1));
                mx = fmaxf(mx, __shfl_xor(mx, 2));
                mx = fmaxf(mx, __shfl_xor(mx, 4));
                mx = fmaxf(mx, __shfl_xor(mx, 8));
                float mn = fmaxf(m_r[i][r], mx);
                float al = __expf(m_r[i][r] - mn);
                float ps = 0.f;
                #pragma unroll
                for (int kj = 0; kj < 4; kj++) {
                    float p = __expf(Sacc[i][kj][r] - mn);
                    Sacc[i][kj][r] = p;
                    ps += p;
                }
                ps += __shfl_xor(ps, 1);
                ps += __shfl_xor(ps, 2);
                ps += __shfl_xor(ps, 4);
                ps += __shfl_xor(ps, 8);
                l_r[i][r] = l_r[i][r] * al + ps;
                m_r[i][r] = mn;
                alpha_[i][r] = al;
            }
        }
        #pragma unroll
        for (int i = 0; i < 2; i++)
            #pragma unroll
            for (int od = 0; od < 4; od++)
                #pragma unroll
                for (int r = 0; r < 4; r++)
                    Oacc[i][od][r] *= alpha_[i][r];

        bf16_t* Pw = Ps[wid];
        #pragma unroll
        for (int i = 0; i < 2; i++)
            #pragma unroll
            for (int kj = 0; kj < 4; kj++)
                #pragma unroll
                for (int r = 0; r < 4; r++)
                    Pw[(i * 16 + lq * 4 + r) * KR + kj * 16 + col] = (bf16_t)Sacc[i][kj][r];
        __syncthreads();

        #pragma unroll
        for (int m = 0; m < 2; m++) {
            bf16x8 afp[2];
            #pragma unroll
            for (int i = 0; i < 2; i++)
                afp[i] = *(const bf16x8*)(Pw + (i * 16 + col) * KR + m * 32 + lq * 8);
            #pragma unroll
            for (int od = 0; od < 4; od++) {
                bf16x8 vf = *(const bf16x8*)(Vt + (od * 16 + col) * KR + m * 32 + lq * 8);
                #pragma unroll
                for (int i = 0; i < 2; i++)
                    Oacc[i][od] = __builtin_amdgcn_mfma_f32_16x16x32_bf16(afp[i], vf, Oacc[i][od], 0, 0, 0);
            }
        }
        __syncthreads();
    }

    bf16_t* Pw = Ps[wid];
    float inv[2][4];
    #pragma unroll
    for (int i = 0; i < 2; i++)
        #pragma unroll
        for (int r = 0; r < 4; r++) inv[i][r] = 1.f / l_r[i][r];
    #pragma unroll
    for (int i = 0; i < 2; i++)
        #pragma unroll
        for (int od = 0; od < 4; od++)
            #pragma unroll
            for (int r = 0; r < 4; r++)
                Pw[(i * 16 + lq * 4 + r) * KR + od * 16 + col] = (bf16_t)(Oacc[i][od][r] * inv[i][r]);
    __syncthreads();
    #pragma unroll
    for (int it = 0; it < 4; it++) {
        int idx = lane + it * 64;
        int row = idx >> 3, g = idx & 7;
        int gs = bi * BLK + qr0 + row;
        *(bf16x8*)(o + ((size_t)(b * SEQ + gs)) * WIDTH + h * DH + g * 8) =
            *(const bf16x8*)(Pw + row * KR + g * 8);
    }
}

extern "C" void kernel_launch(void* const* d_in, const int* in_sizes, int n_in,
                              void* d_out, int out_size, void* d_ws, size_t ws_size,
                              hipStream_t stream) {
    const float* x     = (const float*)d_in[0];
    const float* f     = (const float*)d_in[1];
    const float* delim = (const float*)d_in[2];
    const float* ln1_s = (const float*)d_in[3];
    const float* ln1_b = (const float*)d_in[4];
    const float* w_qkv = (const float*)d_in[5];
    const float* b_qkv = (const float*)d_in[6];
    const float* w_out = (const float*)d_in[7];
    const float* b_out = (const float*)d_in[8];
    const float* ln2_s = (const float*)d_in[9];
    const float* ln2_b = (const float*)d_in[10];
    const float* w_fc  = (const float*)d_in[11];
    const float* b_fc  = (const float*)d_in[12];
    const float* w_pr  = (const float*)d_in[13];
    const float* b_pr  = (const float*)d_in[14];
    const float* w_hd  = (const float*)d_in[15];
    float* out = (float*)d_out;

    // workspace layout (~89 MB):
    // h fp32 (14.35) | big_bf MPAD x 2048 (28.8; qkv uses 1536-wide, o_bf aliases tail)
    // | a_bf MPAD x 512 (7.2; gather head buffer aliases it) | bf16 weights (38.8,
    //   contiguous in cast_all segment order: wi, wo, wfc, wpr, wh)
    char* base = (char*)d_ws;
    float*  h      = (float*)base;    base += (size_t)MROWS * WIDTH * 4;
    bf16_t* big_bf = (bf16_t*)base;   base += (size_t)MPAD * 2048 * 2;
    bf16_t* o_bf   = big_bf + (size_t)MPAD * 1536;   // tail alias: MPAD*512 bf16
    bf16_t* a_bf   = (bf16_t*)base;   base += (size_t)MPAD * 512 * 2;
    bf16_t* g_bf   = a_bf;            // head gather buffer (post-layers lifetime)
    bf16_t* wi_bf  = (bf16_t*)base;   base += (size_t)LAYERS * 1536 * 512 * 2;
    bf16_t* wo_bf  = (bf16_t*)base;   base += (size_t)LAYERS * 512 * 512 * 2;
    bf16_t* wfc_bf = (bf16_t*)base;   base += (size_t)LAYERS * 2048 * 512 * 2;
    bf16_t* wpr_bf = (bf16_t*)base;   base += (size_t)LAYERS * 512 * 2048 * 2;
    bf16_t* wh_bf  = (bf16_t*)base;   base += (size_t)VOCAB * 512 * 2;

    // hoisted weight casts: ONE kernel over all 5 segments (outputs contiguous)
    {
        const int n0 = LAYERS * 1536 * 512 / 4;
        const int n1 = LAYERS * 512 * 512 / 4;
        const int n2 = LAYERS * 2048 * 512 / 4;
        const int n3 = LAYERS * 512 * 2048 / 4;
        const int n4c = VOCAB * 512 / 4;
        const int ntot = n0 + n1 + n2 + n3 + n4c;
        cast_all_kernel<<<(ntot + 255) / 256, 256, 0, stream>>>(
            w_qkv, w_out, w_fc, w_pr, w_hd, wi_bf, n0, n1, n2, n3, ntot);
    }

    embed_kernel<<<(BATCH * SEQ * WIDTH) / 256, 256, 0, stream>>>(x, f, delim, h);

    const int MT = (MROWS + TM - 1) / TM;   // 55
    for (int l = 0; l < LAYERS; l++) {
        ln_bf16_kernel<<<MROWS / 4, 256, 0, stream>>>(h, ln1_s + l * WIDTH, ln1_b + l * WIDTH, a_bf);
        gemm_f<3, 128><<<dim3(1536 / 128, MT), 256, 0, stream>>>(
            a_bf, wi_bf + (size_t)l * 1536 * 512, b_qkv + (size_t)l * 1536,
            nullptr, big_bf, MROWS, 1536, 512);
        attn_mfma<<<dim3(NFR, HEADS, BATCH), 256, 0, stream>>>(big_bf, o_bf);
        gemm_f<2, 64><<<dim3(512 / 64, MT), 256, 0, stream>>>(
            o_bf, wo_bf + (size_t)l * 512 * 512, b_out + (size_t)l * 512,
            h, nullptr, MROWS, 512, 512);
        ln_bf16_kernel<<<MROWS / 4, 256, 0, stream>>>(h, ln2_s + l * WIDTH, ln2_b + l * WIDTH, a_bf);
        gemm_f<1, 128><<<dim3(2048 / 128, MT), 256, 0, stream>>>(
            a_bf, wfc_bf + (size_t)l * 2048 * 512, b_fc + (size_t)l * 2048,
            nullptr, big_bf, MROWS, 2048, 512);
        gemm_f<2, 64><<<dim3(512 / 64, MT), 256, 0, stream>>>(
            big_bf, wpr_bf + (size_t)l * 512 * 2048, b_pr + (size_t)l * 512,
            h, nullptr, MROWS, 512, 2048);
    }

    gather_bf16_kernel<<<OUTROWS * 64 / 256, 256, 0, stream>>>(h, g_bf);
    gemm_f<0, 64><<<dim3(VOCAB / 64, OUTROWS / TM), 256, 0, stream>>>(
        g_bf, wh_bf, nullptr, out, nullptr, OUTROWS, VOCAB, 512);
}